// Round 6
// baseline (365.379 us; speedup 1.0000x reference)
//
#include <hip/hip_runtime.h>
#include <hip/hip_bf16.h>
#include <stdint.h>

#define E_ 8
#define H_ 2048
#define I_ 1408
#define T_ 2048
#define K_ 2
#define G_ 128

#define ITILES_ 22            // I_/64   (gemm1 i-tiles)
#define HTILES_ 16            // H_/128  (gemm2 h-tiles)
#define NT1_ 32               // H_/64 K-steps (gemm1)
#define NT2_ 22               // I_/64 K-steps (gemm2)
#define U32_PER_EXP_ 360448   // u32 per expert per matrix (I_*H_/8 == H_*I_/8)
#define U2_PER_EXP_  180224   // uint2 per expert per matrix
#define U2_PER_MAT_  1441792  // uint2 per matrix (8 experts)

typedef __bf16 bf16;
typedef bf16 bf16x8 __attribute__((ext_vector_type(8)));
typedef float f32x4 __attribute__((ext_vector_type(4)));

__device__ __forceinline__ uint32_t prm(uint32_t hi, uint32_t lo, uint32_t sel) {
    return __builtin_amdgcn_perm(hi, lo, sel);
}

// Scale-folded dequant tables: bf16(e2m1[m]*s) split into high/low byte LUTs.
struct DequantTab { uint32_t thi0, thi1, tlo0, tlo1; };

__device__ __forceinline__ DequantTab build_tab(float s) {
    union { bf16 h[8]; uint32_t u[4]; } tb;
    tb.h[0] = (bf16)(0.0f);
    tb.h[1] = (bf16)(0.5f * s);
    tb.h[2] = (bf16)(1.0f * s);
    tb.h[3] = (bf16)(1.5f * s);
    tb.h[4] = (bf16)(2.0f * s);
    tb.h[5] = (bf16)(3.0f * s);
    tb.h[6] = (bf16)(4.0f * s);
    tb.h[7] = (bf16)(6.0f * s);
    DequantTab t;
    t.thi0 = prm(tb.u[1], tb.u[0], 0x07050301u);
    t.tlo0 = prm(tb.u[1], tb.u[0], 0x06040200u);
    t.thi1 = prm(tb.u[3], tb.u[2], 0x07050301u);
    t.tlo1 = prm(tb.u[3], tb.u[2], 0x06040200u);
    return t;
}

// 8 fp4 (one u32, k-order) -> 8 scaled bf16 as uint4. ~21 VALU ops.
__device__ __forceinline__ uint4 dequant8t(uint32_t p, const DequantTab& t) {
    const uint32_t pr = p >> 4;
    const uint32_t pe = p  & 0x07070707u;
    const uint32_t po = pr & 0x07070707u;
    const uint32_t He = prm(t.thi1, t.thi0, pe) | ((p  & 0x08080808u) << 4);
    const uint32_t Le = prm(t.tlo1, t.tlo0, pe);
    const uint32_t Ho = prm(t.thi1, t.thi0, po) | ((pr & 0x08080808u) << 4);
    const uint32_t Lo = prm(t.tlo1, t.tlo0, po);
    const uint32_t E01 = prm(He, Le, 0x05010400u);
    const uint32_t E23 = prm(He, Le, 0x07030602u);
    const uint32_t O01 = prm(Ho, Lo, 0x05010400u);
    const uint32_t O23 = prm(Ho, Lo, 0x07030602u);
    return make_uint4(prm(O01, E01, 0x05040100u),
                      prm(O01, E01, 0x07060302u),
                      prm(O23, E23, 0x05040100u),
                      prm(O23, E23, 0x07060302u));
}

__device__ __forceinline__ bf16x8 dq_frag(uint32_t p, const DequantTab& t) {
    union { uint4 u; bf16x8 v; } r;
    r.u = dequant8t(p, t);
    return r.v;
}

// async 16B global -> LDS DMA (wave-uniform-base + lane-linear dest)
__device__ __forceinline__ void gld16(void* lds, const void* g) {
    __builtin_amdgcn_global_load_lds(
        (__attribute__((address_space(1))) void*)g,
        (__attribute__((address_space(3))) void*)lds, 16, 0, 0);
}

#define SB0() __builtin_amdgcn_sched_barrier(0)

// ---------------- routing ----------------
__global__ void route_count(const int* __restrict__ topk_idx, int* __restrict__ counts) {
    int p = blockIdx.x * blockDim.x + threadIdx.x;
    if (p < T_ * K_) atomicAdd(&counts[topk_idx[p]], 1);
}

// 5 fixed 128-token tile-slots per expert; slot 4 loops on overflow.
__global__ void route_scan(const int* __restrict__ counts, int* __restrict__ offsets,
                           int* __restrict__ tmap) {
    if (threadIdx.x == 0) {
        int acc = 0;
        for (int e = 0; e < E_; e++) { offsets[e] = acc; acc += counts[e]; }
        offsets[E_] = acc;
        for (int s = 0; s < 40; s++) tmap[s] = -1;
        for (int e = 0; e < E_; e++) {
            int nt = (counts[e] + 127) >> 7;
            if (nt > 5) nt = 5;
            for (int j = 0; j < nt; j++) tmap[e * 5 + j] = (e << 16) | j;
        }
    }
}

__global__ void route_fill(const int* __restrict__ topk_idx, const float* __restrict__ topk_w,
                           int* __restrict__ cursors, const int* __restrict__ offsets,
                           int* __restrict__ tok, float* __restrict__ wgt) {
    int p = blockIdx.x * blockDim.x + threadIdx.x;
    if (p < T_ * K_) {
        int e = topk_idx[p];
        int slot = atomicAdd(&cursors[e], 1);
        int idx = offsets[e] + slot;
        tok[idx] = p / K_;
        wgt[idx] = topk_w[p];
    }
}

// x f32 -> bf16
__global__ __launch_bounds__(256)
void xcast_kernel(const float* __restrict__ x, uint4* __restrict__ xb) {
    const int i = blockIdx.x * 256 + threadIdx.x;
    const float4 a = ((const float4*)x)[i * 2];
    const float4 b = ((const float4*)x)[i * 2 + 1];
    union { uint4 u; bf16 h[8]; } r;
    r.h[0] = (bf16)a.x; r.h[1] = (bf16)a.y; r.h[2] = (bf16)a.z; r.h[3] = (bf16)a.w;
    r.h[4] = (bf16)b.x; r.h[5] = (bf16)b.y; r.h[6] = (bf16)b.z; r.h[7] = (bf16)b.w;
    xb[i] = r.u;
}

// ---------------- weight repack: fragment order ----------------
// gemm1 dest (u32): [mat][e][it 22][t 32][wx 2][ni 2][lane 64][kh 2]
// src u32 (row,c): row = it*64+wx*32+ni*16+(l&15), c = t*8+kh*4+(l>>4)
__global__ __launch_bounds__(256)
void repack_gu_kernel(const uint32_t* __restrict__ gate_packed,
                      const uint32_t* __restrict__ up_packed,
                      uint32_t* __restrict__ rgu) {
    const int e = blockIdx.z, mat = blockIdx.y;
    const int tid = blockIdx.x * 256 + threadIdx.x;      // 0..360447 (coalesced read)
    const uint32_t* src = (mat ? up_packed : gate_packed) + (size_t)e * (I_ * (H_ / 8));
    const uint32_t v = src[tid];
    const int i = tid >> 8, c = tid & 255;
    const int it = i >> 6, rr = i & 63;
    const int wx = rr >> 5, ni = (rr >> 4) & 1, lr = rr & 15;
    const int t = c >> 3, cc = c & 7;
    const int kh = cc >> 2, kq = cc & 3, l = kq * 16 + lr;
    const int dstidx = ((((it * 32 + t) * 2 + wx) * 2 + ni) * 64 + l) * 2 + kh;
    rgu[(size_t)mat * (2 * U2_PER_MAT_) + (size_t)e * U32_PER_EXP_ + dstidx] = v;
}

// gemm2 dest (u32): [e][ht 16][t 22][wx 2][ni 4][lane 64][kh 2]
// src: row = ht*128+wx*64+ni*16+(l&15), c = t*8+kh*4+(l>>4)
__global__ __launch_bounds__(256)
void repack_down_kernel(const uint32_t* __restrict__ down_packed,
                        uint32_t* __restrict__ rd) {
    const int e = blockIdx.z;
    const int tid = blockIdx.x * 256 + threadIdx.x;      // 0..360447
    const uint32_t* src = down_packed + (size_t)e * (H_ * (I_ / 8));
    const uint32_t v = src[tid];
    const int i = tid / 176, c = tid - i * 176;
    const int ht = i >> 7, rr = i & 127;
    const int wx = rr >> 6, ni = (rr >> 4) & 3, lr = rr & 15;
    const int t = c >> 3, cc = c & 7;
    const int kh = cc >> 2, kq = cc & 3, l = kq * 16 + lr;
    const int dstidx = ((((ht * 22 + t) * 2 + wx) * 4 + ni) * 64 + l) * 2 + kh;
    rd[(size_t)e * U32_PER_EXP_ + dstidx] = v;
}

// ---------------- GEMM1: 256 thr, 128tok x 64i (gate+up), BK=64 ----------------
// Fragment-direct B (no weight LDS: LDS traffic 96->48 KB/step). (256,2) so the
// allocator is NOT reg-capped (R4's (256,4) forced 64 VGPR -> 527MB spill).
__global__ __launch_bounds__(256, 2)
void gemm1t_kernel(const bf16* __restrict__ xb,
                   const uint2* __restrict__ rgu,
                   const float* __restrict__ gate_scales,
                   const float* __restrict__ up_scales,
                   const int* __restrict__ offsets,
                   const int* __restrict__ tmap,
                   const int* __restrict__ tok, bf16* __restrict__ h_buf)
{
    const int bid = blockIdx.x;
    const int x8 = bid & 7;
    const int r = bid >> 3;              // 0..109
    const int t5 = r / ITILES_;
    const int itile = r - t5 * ITILES_;  // 0..21
    const int tm = tmap[x8 * 5 + t5];
    if (tm < 0) return;
    const int e = tm >> 16, j0 = tm & 0xffff;
    const int row0 = offsets[e];
    const int cnt = offsets[e + 1] - row0;
    const int nch = (cnt + 127) >> 7;
    const int chend = (j0 == 4) ? nch : (j0 + 1);

    __shared__ __align__(16) bf16 xs[2][128][64];    // 32 KB only

    const int tid = threadIdx.x;
    const int wave = __builtin_amdgcn_readfirstlane(tid >> 6);
    const int lane = tid & 63;
    const int wy = wave >> 1, wx = wave & 1;
    const int lrow = lane & 15, kq = lane >> 4;

    // fragment-order weight base for this (e, itile, wx): +t*256, +ni*64
    const uint2* gb = rgu + (size_t)e * U2_PER_EXP_ + (itile * 128 + wx * 2) * 64 + lane;
    const float* gsc = gate_scales + (size_t)e * (H_ / G_) * I_;
    const float* usc = up_scales + (size_t)e * (H_ / G_) * I_;
    const int rb0 = itile * 64 + wx * 32 + lrow;     // ni=1 at +16

    const int xr = tid >> 3, xc = tid & 7;
    const int xch = (xc ^ (xr & 7)) * 8;

    constexpr int NG = H_ / G_;          // 16
    constexpr int NT = NT1_;             // 32

    for (int ch = j0; ch < chend; ++ch) {
        const bf16* xsrc[4];
        bf16* xdst[4];
#pragma unroll
        for (int j = 0; j < 4; ++j) {
            int g = ch * 128 + xr + j * 32;
            g = (g < cnt) ? g : (cnt - 1);
            xsrc[j] = xb + (size_t)tok[row0 + g] * H_ + xch;
            xdst[j] = &xs[0][xr + j * 32][xc * 8];
        }

        f32x4 accg[4][2] = {};
        f32x4 accu[4][2] = {};
        float sc[2][2];
        uint2 pwc[2][2], pwn[2][2];

        // prologue order: sc(0) -> DMA(0) -> pw(0)
        sc[0][0] = gsc[rb0]; sc[0][1] = gsc[rb0 + 16];
        sc[1][0] = usc[rb0]; sc[1][1] = usc[rb0 + 16];
        SB0();
#pragma unroll
        for (int j = 0; j < 4; ++j) gld16(xdst[j], xsrc[j]);
        SB0();
        pwc[0][0] = gb[0];            pwc[0][1] = gb[64];
        pwc[1][0] = gb[U2_PER_MAT_];  pwc[1][1] = gb[U2_PER_MAT_ + 64];
        SB0();

        for (int kg = 0; kg < NG; ++kg) {
            DequantTab tab[2][2];
#pragma unroll
            for (int m = 0; m < 2; ++m)
#pragma unroll
                for (int n = 0; n < 2; ++n)
                    tab[m][n] = build_tab(sc[m][n]);   // auto-wait drains sc only
            const int t0 = kg * 2;

            // ==== even step t0 (buf 0): drain DMA(t0), keep pw(t0) ====
            asm volatile("s_waitcnt vmcnt(4) lgkmcnt(0)" ::: "memory");
            __builtin_amdgcn_s_barrier();
            SB0();
            {   // issue t0+1 (always exists): DMA -> buf1, pw, sc(kg+1)
#pragma unroll
                for (int j = 0; j < 4; ++j)
                    gld16(xdst[j] + 128 * 64, xsrc[j] + (t0 + 1) * 64);
                SB0();
                const uint2* gt = gb + (size_t)(t0 + 1) * 256;
                pwn[0][0] = gt[0];            pwn[0][1] = gt[64];
                pwn[1][0] = gt[U2_PER_MAT_];  pwn[1][1] = gt[U2_PER_MAT_ + 64];
                const int kgn = (kg + 1 < NG) ? kg + 1 : kg;
                sc[0][0] = gsc[kgn * I_ + rb0]; sc[0][1] = gsc[kgn * I_ + rb0 + 16];
                sc[1][0] = usc[kgn * I_ + rb0]; sc[1][1] = usc[kgn * I_ + rb0 + 16];
                SB0();
            }
#pragma unroll
            for (int kh = 0; kh < 2; ++kh) {
                bf16x8 a[4], bg[2], bu[2];
#pragma unroll
                for (int mi = 0; mi < 4; ++mi) {
                    const int ra = wy * 64 + mi * 16 + lrow;
                    a[mi] = *(const bf16x8*)&xs[0][ra][((kh * 4 + kq) ^ (ra & 7)) * 8];
                }
#pragma unroll
                for (int n = 0; n < 2; ++n) {
                    bg[n] = dq_frag(kh ? pwc[0][n].y : pwc[0][n].x, tab[0][n]);
                    bu[n] = dq_frag(kh ? pwc[1][n].y : pwc[1][n].x, tab[1][n]);
                }
#pragma unroll
                for (int mi = 0; mi < 4; ++mi)
#pragma unroll
                    for (int n = 0; n < 2; ++n) {
                        accg[mi][n] = __builtin_amdgcn_mfma_f32_16x16x32_bf16(a[mi], bg[n], accg[mi][n], 0, 0, 0);
                        accu[mi][n] = __builtin_amdgcn_mfma_f32_16x16x32_bf16(a[mi], bu[n], accu[mi][n], 0, 0, 0);
                    }
            }
#pragma unroll
            for (int m = 0; m < 2; ++m)
#pragma unroll
                for (int n = 0; n < 2; ++n) pwc[m][n] = pwn[m][n];
            SB0();

            // ==== odd step t1 (buf 1): drain DMA(t1), keep pw(t1)+sc ====
            const int t1 = t0 + 1;
            asm volatile("s_waitcnt vmcnt(8) lgkmcnt(0)" ::: "memory");
            __builtin_amdgcn_s_barrier();
            SB0();
            if (t1 < NT - 1) {
#pragma unroll
                for (int j = 0; j < 4; ++j)
                    gld16(xdst[j], xsrc[j] + (t1 + 1) * 64);
                SB0();
                const uint2* gt = gb + (size_t)(t1 + 1) * 256;
                pwn[0][0] = gt[0];            pwn[0][1] = gt[64];
                pwn[1][0] = gt[U2_PER_MAT_];  pwn[1][1] = gt[U2_PER_MAT_ + 64];
                SB0();
            }
#pragma unroll
            for (int kh = 0; kh < 2; ++kh) {
                bf16x8 a[4], bg[2], bu[2];
#pragma unroll
                for (int mi = 0; mi < 4; ++mi) {
                    const int ra = wy * 64 + mi * 16 + lrow;
                    a[mi] = *(const bf16x8*)&xs[1][ra][((kh * 4 + kq) ^ (ra & 7)) * 8];
                }
#pragma unroll
                for (int n = 0; n < 2; ++n) {
                    bg[n] = dq_frag(kh ? pwc[0][n].y : pwc[0][n].x, tab[0][n]);
                    bu[n] = dq_frag(kh ? pwc[1][n].y : pwc[1][n].x, tab[1][n]);
                }
#pragma unroll
                for (int mi = 0; mi < 4; ++mi)
#pragma unroll
                    for (int n = 0; n < 2; ++n) {
                        accg[mi][n] = __builtin_amdgcn_mfma_f32_16x16x32_bf16(a[mi], bg[n], accg[mi][n], 0, 0, 0);
                        accu[mi][n] = __builtin_amdgcn_mfma_f32_16x16x32_bf16(a[mi], bu[n], accu[mi][n], 0, 0, 0);
                    }
            }
            if (t1 < NT - 1) {
#pragma unroll
                for (int m = 0; m < 2; ++m)
#pragma unroll
                    for (int n = 0; n < 2; ++n) pwc[m][n] = pwn[m][n];
            }
            SB0();
        }

        // epilogue: h = silu(g)*u. C layout: col=lane&15, row=(lane>>4)*4+r
#pragma unroll
        for (int mi = 0; mi < 4; ++mi)
#pragma unroll
            for (int n = 0; n < 2; ++n) {
                const int icol = itile * 64 + wx * 32 + n * 16 + lrow;
#pragma unroll
                for (int rr = 0; rr < 4; ++rr) {
                    const int grow = ch * 128 + wy * 64 + mi * 16 + kq * 4 + rr;
                    if (grow < cnt) {
                        const float gv = accg[mi][n][rr];
                        const float hv = gv / (1.f + __expf(-gv)) * accu[mi][n][rr];
                        h_buf[(size_t)(row0 + grow) * I_ + icol] = (bf16)hv;
                    }
                }
            }
    }
}

// ---------------- GEMM2: 256 thr, 128tok x 128h, BK=64, atomic combine ----------------
__global__ __launch_bounds__(256, 2)
void gemm2t_kernel(const bf16* __restrict__ h_buf,
                   const uint2* __restrict__ rd,
                   const float* __restrict__ down_scales,
                   const int* __restrict__ offsets,
                   const int* __restrict__ tmap,
                   const int* __restrict__ tok,
                   const float* __restrict__ wgt, float* __restrict__ out)
{
    const int bid = blockIdx.x;
    const int x8 = bid & 7;
    const int r = bid >> 3;              // 0..79
    const int t5 = r >> 4;
    const int htile = r & 15;            // 0..15
    const int tm = tmap[x8 * 5 + t5];
    if (tm < 0) return;
    const int e = tm >> 16, j0 = tm & 0xffff;
    const int row0 = offsets[e];
    const int cnt = offsets[e + 1] - row0;
    const int nch = (cnt + 127) >> 7;
    const int chend = (j0 == 4) ? nch : (j0 + 1);

    __shared__ __align__(16) bf16 hs[2][128][64];

    const int tid = threadIdx.x;
    const int wave = __builtin_amdgcn_readfirstlane(tid >> 6);
    const int lane = tid & 63;
    const int wy = wave >> 1, wx = wave & 1;
    const int lrow = lane & 15, kq = lane >> 4;

    const uint2* db = rd + (size_t)e * U2_PER_EXP_ + (htile * 176 + wx * 4) * 64 + lane;
    const float* dsc = down_scales + (size_t)e * (I_ / G_) * H_;
    const int rb0 = htile * 128 + wx * 64 + lrow;    // ni at +16*ni

    const int xr = tid >> 3, xc = tid & 7;
    const int xch = (xc ^ (xr & 7)) * 8;

    constexpr int NG = I_ / G_;          // 11
    constexpr int NT = NT2_;             // 22

    for (int ch = j0; ch < chend; ++ch) {
        const bf16* hsrc[4];
        bf16* hdst[4];
#pragma unroll
        for (int j = 0; j < 4; ++j) {
            int g = ch * 128 + xr + j * 32;
            g = (g < cnt) ? g : (cnt - 1);
            hsrc[j] = h_buf + (size_t)(row0 + g) * I_ + xch;
            hdst[j] = &hs[0][xr + j * 32][xc * 8];
        }

        f32x4 acc[4][4] = {};
        float sc[4];
        uint2 pwc[4], pwn[4];

        sc[0] = dsc[rb0]; sc[1] = dsc[rb0 + 16]; sc[2] = dsc[rb0 + 32]; sc[3] = dsc[rb0 + 48];
        SB0();
#pragma unroll
        for (int j = 0; j < 4; ++j) gld16(hdst[j], hsrc[j]);
        SB0();
#pragma unroll
        for (int n = 0; n < 4; ++n) pwc[n] = db[n * 64];
        SB0();

        for (int kg = 0; kg < NG; ++kg) {
            DequantTab tab[4];
#pragma unroll
            for (int n = 0; n < 4; ++n) tab[n] = build_tab(sc[n]);
            const int t0 = kg * 2;

            // ==== even step ====
            asm volatile("s_waitcnt vmcnt(4) lgkmcnt(0)" ::: "memory");
            __builtin_amdgcn_s_barrier();
            SB0();
            {
#pragma unroll
                for (int j = 0; j < 4; ++j)
                    gld16(hdst[j] + 128 * 64, hsrc[j] + (t0 + 1) * 64);
                SB0();
                const uint2* dt = db + (size_t)(t0 + 1) * 512;
#pragma unroll
                for (int n = 0; n < 4; ++n) pwn[n] = dt[n * 64];
                const int kgn = (kg + 1 < NG) ? kg + 1 : kg;
                sc[0] = dsc[kgn * H_ + rb0];      sc[1] = dsc[kgn * H_ + rb0 + 16];
                sc[2] = dsc[kgn * H_ + rb0 + 32]; sc[3] = dsc[kgn * H_ + rb0 + 48];
                SB0();
            }
#pragma unroll
            for (int kh = 0; kh < 2; ++kh) {
                bf16x8 a[4], b[4];
#pragma unroll
                for (int mi = 0; mi < 4; ++mi) {
                    const int ra = wy * 64 + mi * 16 + lrow;
                    a[mi] = *(const bf16x8*)&hs[0][ra][((kh * 4 + kq) ^ (ra & 7)) * 8];
                }
#pragma unroll
                for (int n = 0; n < 4; ++n)
                    b[n] = dq_frag(kh ? pwc[n].y : pwc[n].x, tab[n]);
#pragma unroll
                for (int mi = 0; mi < 4; ++mi)
#pragma unroll
                    for (int n = 0; n < 4; ++n)
                        acc[mi][n] = __builtin_amdgcn_mfma_f32_16x16x32_bf16(a[mi], b[n], acc[mi][n], 0, 0, 0);
            }
#pragma unroll
            for (int n = 0; n < 4; ++n) pwc[n] = pwn[n];
            SB0();

            // ==== odd step ====
            const int t1 = t0 + 1;
            asm volatile("s_waitcnt vmcnt(8) lgkmcnt(0)" ::: "memory");
            __builtin_amdgcn_s_barrier();
            SB0();
            if (t1 < NT - 1) {
#pragma unroll
                for (int j = 0; j < 4; ++j)
                    gld16(hdst[j], hsrc[j] + (t1 + 1) * 64);
                SB0();
                const uint2* dt = db + (size_t)(t1 + 1) * 512;
#pragma unroll
                for (int n = 0; n < 4; ++n) pwn[n] = dt[n * 64];
                SB0();
            }
#pragma unroll
            for (int kh = 0; kh < 2; ++kh) {
                bf16x8 a[4], b[4];
#pragma unroll
                for (int mi = 0; mi < 4; ++mi) {
                    const int ra = wy * 64 + mi * 16 + lrow;
                    a[mi] = *(const bf16x8*)&hs[1][ra][((kh * 4 + kq) ^ (ra & 7)) * 8];
                }
#pragma unroll
                for (int n = 0; n < 4; ++n)
                    b[n] = dq_frag(kh ? pwc[n].y : pwc[n].x, tab[n]);
#pragma unroll
                for (int mi = 0; mi < 4; ++mi)
#pragma unroll
                    for (int n = 0; n < 4; ++n)
                        acc[mi][n] = __builtin_amdgcn_mfma_f32_16x16x32_bf16(a[mi], b[n], acc[mi][n], 0, 0, 0);
            }
            if (t1 < NT - 1) {
#pragma unroll
                for (int n = 0; n < 4; ++n) pwc[n] = pwn[n];
            }
            SB0();
        }

        // epilogue: atomic combine (each out element gets exactly K_=2 adds)
#pragma unroll
        for (int mi = 0; mi < 4; ++mi)
#pragma unroll
            for (int rr = 0; rr < 4; ++rr) {
                const int grow = ch * 128 + wy * 64 + mi * 16 + kq * 4 + rr;
                if (grow < cnt) {
                    const int slot = row0 + grow;
                    const float w = wgt[slot];
                    const int tk = tok[slot];
#pragma unroll
                    for (int n = 0; n < 4; ++n) {
                        const int col = htile * 128 + wx * 64 + n * 16 + lrow;
                        atomicAdd(out + (size_t)tk * H_ + col, acc[mi][n][rr] * w);
                    }
                }
            }
    }
}

extern "C" void kernel_launch(void* const* d_in, const int* in_sizes, int n_in,
                              void* d_out, int out_size, void* d_ws, size_t ws_size,
                              hipStream_t stream) {
    const float* x = (const float*)d_in[0];
    const uint32_t* gate_packed = (const uint32_t*)d_in[1];
    const float* gate_scales = (const float*)d_in[2];
    const uint32_t* up_packed = (const uint32_t*)d_in[3];
    const float* up_scales = (const float*)d_in[4];
    const uint32_t* down_packed = (const uint32_t*)d_in[5];
    const float* down_scales = (const float*)d_in[6];
    const int* topk_idx = (const int*)d_in[7];
    const float* topk_w = (const float*)d_in[8];
    float* out = (float*)d_out;

    // workspace layout (bytes), total 43.0 MB:
    //   [0..640)        counts/cursors/offsets/tmap
    //   [640..33408)    tok, wgt
    //   [49792..+11.5M) h_buf  (bf16 4096x1408)
    //   [+..+8.4M)      xb     (bf16 2048x2048)          -- dead after gemm1
    //   [+..+23.1M)     rgu    (repacked gate+up u32)    -- dead after gemm1
    //   rd (repacked down, 11.5M) overlays xb, written AFTER gemm1.
    char* ws = (char*)d_ws;
    int* counts  = (int*)ws;
    int* cursors = (int*)(ws + 32);
    int* offsets = (int*)(ws + 64);
    int* tmap    = (int*)(ws + 128);
    int* tok     = (int*)(ws + 640);
    float* wgt   = (float*)(ws + 17024);
    bf16* h_buf  = (bf16*)(ws + 49792);
    char* xb_rd  = ws + 49792 + 11534336ull;
    bf16* xb     = (bf16*)xb_rd;
    uint32_t* rd = (uint32_t*)xb_rd;                       // overlays xb (after gemm1)
    uint32_t* rgu = (uint32_t*)(xb_rd + 8388608ull);

    hipMemsetAsync(d_ws, 0, 1024, stream);
    hipMemsetAsync(d_out, 0, out_size, stream);

    route_count<<<(T_ * K_ + 255) / 256, 256, 0, stream>>>(topk_idx, counts);
    route_scan<<<1, 64, 0, stream>>>(counts, offsets, tmap);
    route_fill<<<(T_ * K_ + 255) / 256, 256, 0, stream>>>(topk_idx, topk_w, cursors, offsets,
                                                          tok, wgt);
    xcast_kernel<<<T_ * H_ / 8 / 256, 256, 0, stream>>>(x, (uint4*)xb);
    repack_gu_kernel<<<dim3(U32_PER_EXP_ / 256, 2, E_), 256, 0, stream>>>(gate_packed, up_packed, rgu);

    gemm1t_kernel<<<dim3(ITILES_ * 5 * E_), 256, 0, stream>>>(xb, (const uint2*)rgu,
                                                              gate_scales, up_scales,
                                                              offsets, tmap, tok, h_buf);
    repack_down_kernel<<<dim3(U32_PER_EXP_ / 256, 1, E_), 256, 0, stream>>>(down_packed, rd);
    gemm2t_kernel<<<dim3(HTILES_ * 5 * E_), 256, 0, stream>>>(h_buf, (const uint2*)rd,
                                                              down_scales, offsets, tmap,
                                                              tok, wgt, out);
}

// Round 7
// 296.197 us; speedup vs baseline: 1.2336x; 1.2336x over previous
//
#include <hip/hip_runtime.h>
#include <hip/hip_bf16.h>
#include <stdint.h>

#define E_ 8
#define H_ 2048
#define I_ 1408
#define T_ 2048
#define K_ 2
#define G_ 128

typedef __bf16 bf16;
typedef bf16 bf16x8 __attribute__((ext_vector_type(8)));
typedef float f32x4 __attribute__((ext_vector_type(4)));

__device__ __forceinline__ uint32_t prm(uint32_t hi, uint32_t lo, uint32_t sel) {
    return __builtin_amdgcn_perm(hi, lo, sel);
}

// Scale-folded dequant tables: bf16(e2m1[m]*s) split into high/low byte LUTs.
struct DequantTab { uint32_t thi0, thi1, tlo0, tlo1; };

__device__ __forceinline__ DequantTab build_tab(float s) {
    union { bf16 h[8]; uint32_t u[4]; } tb;
    tb.h[0] = (bf16)(0.0f);
    tb.h[1] = (bf16)(0.5f * s);
    tb.h[2] = (bf16)(1.0f * s);
    tb.h[3] = (bf16)(1.5f * s);
    tb.h[4] = (bf16)(2.0f * s);
    tb.h[5] = (bf16)(3.0f * s);
    tb.h[6] = (bf16)(4.0f * s);
    tb.h[7] = (bf16)(6.0f * s);
    DequantTab t;
    t.thi0 = prm(tb.u[1], tb.u[0], 0x07050301u);
    t.tlo0 = prm(tb.u[1], tb.u[0], 0x06040200u);
    t.thi1 = prm(tb.u[3], tb.u[2], 0x07050301u);
    t.tlo1 = prm(tb.u[3], tb.u[2], 0x06040200u);
    return t;
}

// 8 fp4 (one u32, k-order) -> 8 scaled bf16 as uint4. ~21 VALU ops.
__device__ __forceinline__ uint4 dequant8t(uint32_t p, const DequantTab& t) {
    const uint32_t pr = p >> 4;
    const uint32_t pe = p  & 0x07070707u;
    const uint32_t po = pr & 0x07070707u;
    const uint32_t He = prm(t.thi1, t.thi0, pe) | ((p  & 0x08080808u) << 4);
    const uint32_t Le = prm(t.tlo1, t.tlo0, pe);
    const uint32_t Ho = prm(t.thi1, t.thi0, po) | ((pr & 0x08080808u) << 4);
    const uint32_t Lo = prm(t.tlo1, t.tlo0, po);
    const uint32_t E01 = prm(He, Le, 0x05010400u);
    const uint32_t E23 = prm(He, Le, 0x07030602u);
    const uint32_t O01 = prm(Ho, Lo, 0x05010400u);
    const uint32_t O23 = prm(Ho, Lo, 0x07030602u);
    return make_uint4(prm(O01, E01, 0x05040100u),
                      prm(O01, E01, 0x07060302u),
                      prm(O23, E23, 0x05040100u),
                      prm(O23, E23, 0x07060302u));
}

__device__ __forceinline__ bf16x8 dq_frag(uint32_t p, const DequantTab& t) {
    union { uint4 u; bf16x8 v; } r;
    r.u = dequant8t(p, t);
    return r.v;
}

// async 16B global -> LDS DMA (wave-uniform-base + lane-linear dest)
__device__ __forceinline__ void gld16(void* lds, const void* g) {
    __builtin_amdgcn_global_load_lds(
        (__attribute__((address_space(1))) void*)g,
        (__attribute__((address_space(3))) void*)lds, 16, 0, 0);
}

#define SB0() __builtin_amdgcn_sched_barrier(0)

// ---------------- routing ----------------
__global__ void route_count(const int* __restrict__ topk_idx, int* __restrict__ counts) {
    int p = blockIdx.x * blockDim.x + threadIdx.x;
    if (p < T_ * K_) atomicAdd(&counts[topk_idx[p]], 1);
}

// tiles of 128 token-pairs (max total tiles = 4096/128 + 8 = 40)
__global__ void route_scan(const int* __restrict__ counts, int* __restrict__ offsets,
                           int* __restrict__ tmap) {
    if (threadIdx.x == 0) {
        int acc = 0, ti = 0;
        for (int e = 0; e < E_; e++) {
            offsets[e] = acc;
            int nt = (counts[e] + 127) >> 7;
            for (int j = 0; j < nt; j++) tmap[ti++] = (e << 16) | j;
            acc += counts[e];
        }
        offsets[E_] = acc;
        for (; ti < 64; ti++) tmap[ti] = -1;
    }
}

__global__ void route_fill(const int* __restrict__ topk_idx, const float* __restrict__ topk_w,
                           int* __restrict__ cursors, const int* __restrict__ offsets,
                           int* __restrict__ tok, float* __restrict__ wgt,
                           int* __restrict__ inv) {
    int p = blockIdx.x * blockDim.x + threadIdx.x;
    if (p < T_ * K_) {
        int e = topk_idx[p];
        int slot = atomicAdd(&cursors[e], 1);
        int idx = offsets[e] + slot;
        tok[idx] = p / K_;
        wgt[idx] = topk_w[p];
        inv[p] = idx;
    }
}

// x f32 -> bf16
__global__ __launch_bounds__(256)
void xcast_kernel(const float* __restrict__ x, uint4* __restrict__ xb) {
    const int i = blockIdx.x * 256 + threadIdx.x;
    const float4 a = ((const float4*)x)[i * 2];
    const float4 b = ((const float4*)x)[i * 2 + 1];
    union { uint4 u; bf16 h[8]; } r;
    r.h[0] = (bf16)a.x; r.h[1] = (bf16)a.y; r.h[2] = (bf16)a.z; r.h[3] = (bf16)a.w;
    r.h[4] = (bf16)b.x; r.h[5] = (bf16)b.y; r.h[6] = (bf16)b.z; r.h[7] = (bf16)b.w;
    xb[i] = r.u;
}

// ---------------- GEMM1: 128tok x 64i (gate+up), BK=64, RAW-u32 weight LDS ----------------
// Weights staged UNdequanted (4 KB/step vs 16); consumers ds_read_b32 the u32
// for their own B-fragment and dequant in-register. LDS/step 96->61 KB,
// footprint 64->44 KB (3 blocks/CU). x path / barriers / epilogue = R5.
__global__ __launch_bounds__(256, 2)
void gemm1t_kernel(const bf16* __restrict__ xb,
                   const uint32_t* __restrict__ gate_packed,
                   const float* __restrict__ gate_scales,
                   const uint32_t* __restrict__ up_packed,
                   const float* __restrict__ up_scales,
                   const int* __restrict__ offsets,
                   const int* __restrict__ tmap,
                   const int* __restrict__ tok, bf16* __restrict__ h_buf)
{
    const int tm = tmap[blockIdx.x];
    if (tm < 0) return;
    const int e = tm >> 16, ty = tm & 0xffff;       // 128-token tile
    const int row0 = offsets[e];
    const int cnt = offsets[e + 1] - row0;
    const int itile = blockIdx.y;                    // 64 i-cols

    __shared__ __align__(16) bf16 xs0[128][64];          // 16 KB
    __shared__ __align__(16) bf16 xs1[128][64];          // 16 KB
    __shared__ __align__(16) uint32_t wraw[2][2][64][12]; // 2buf x 2mat x 64r x (8+4pad) = 12 KB

    const int tid = threadIdx.x;

    // --- x staging roles: 4 gld16/thread/step, swizzled source chunk ---
    const int xr = tid >> 3;             // 0..31
    const int xc = tid & 7;
    const int xch = (xc ^ (xr & 7)) * 8;
    const bf16* xsrc[4];
    bf16 *xdst0[4], *xdst1[4];
#pragma unroll
    for (int j = 0; j < 4; ++j) {
        int g = ty * 128 + xr + j * 32;
        g = (g < cnt) ? g : (cnt - 1);
        xsrc[j] = xb + (size_t)tok[row0 + g] * H_ + xch;
        xdst0[j] = &xs0[xr + j * 32][xc * 8];
        xdst1[j] = &xs1[xr + j * 32][xc * 8];
    }

    // --- weight staging roles: 1 uint4 (4 u32) per thread/step, RAW ---
    const int mat  = tid >> 7;           // 0 = gate, 1 = up
    const int id   = tid & 127;
    const int wrow = id >> 1;            // 0..63
    const int quad = id & 1;
    const int irow = itile * 64 + wrow;
    const uint32_t* wp_row = (mat ? up_packed : gate_packed)
        + (size_t)e * I_ * (H_ / 8) + (size_t)irow * (H_ / 8) + quad * 4;

    const int wave = tid >> 6, lane = tid & 63;
    const int wy = wave >> 1, wx = wave & 1;
    const int lrow = lane & 15, kq = lane >> 4;

    // consumer scale addressing: per output column rb0 (+16 for ni=1)
    const float* gsc = gate_scales + (size_t)e * (H_ / G_) * I_;
    const float* usc = up_scales + (size_t)e * (H_ / G_) * I_;
    const int rb0 = itile * 64 + wx * 32 + lrow;
    const int rbr0 = wx * 32 + lrow;     // LDS weight row, ni=1 at +16

    f32x4 accg[4][2] = {};
    f32x4 accu[4][2] = {};

    constexpr int NG = H_ / G_;          // 16 kg; 32 K-steps
    constexpr int NT = 2 * NG;

#define MFMA1(XS, WB) do { \
    _Pragma("unroll") \
    for (int kh = 0; kh < 2; ++kh) { \
        bf16x8 a[4], bg[2], bu[2]; \
        _Pragma("unroll") \
        for (int mi = 0; mi < 4; ++mi) { \
            const int ra = wy * 64 + mi * 16 + lrow; \
            a[mi] = *(const bf16x8*)&XS[ra][((kh * 4 + kq) ^ (ra & 7)) * 8]; \
        } \
        _Pragma("unroll") \
        for (int n = 0; n < 2; ++n) { \
            bg[n] = dq_frag(wraw[WB][0][rbr0 + n * 16][kh * 4 + kq], tab[0][n]); \
            bu[n] = dq_frag(wraw[WB][1][rbr0 + n * 16][kh * 4 + kq], tab[1][n]); \
        } \
        _Pragma("unroll") \
        for (int mi = 0; mi < 4; ++mi) \
            _Pragma("unroll") \
            for (int n = 0; n < 2; ++n) { \
                accg[mi][n] = __builtin_amdgcn_mfma_f32_16x16x32_bf16(a[mi], bg[n], accg[mi][n], 0, 0, 0); \
                accu[mi][n] = __builtin_amdgcn_mfma_f32_16x16x32_bf16(a[mi], bu[n], accu[mi][n], 0, 0, 0); \
            } \
    } \
} while (0)

    // ---------------- prologue: DMA(0), pw(0..2), sc(0); raw-write w(0) ----------------
#pragma unroll
    for (int j = 0; j < 4; ++j) gld16(xdst0[j], xsrc[j]);
    SB0();
    uint4 pw0 = *(const uint4*)(wp_row);
    uint4 pwA = *(const uint4*)(wp_row + 8);     // for write at step 0 (w(1))
    uint4 pwB = *(const uint4*)(wp_row + 16);    // for write at step 1 (w(2))
    float sc[2][2], scn[2][2];
    sc[0][0] = gsc[rb0]; sc[0][1] = gsc[rb0 + 16];
    sc[1][0] = usc[rb0]; sc[1][1] = usc[rb0 + 16];
    SB0();
    *(uint4*)&wraw[0][mat][wrow][quad * 4] = pw0;
    asm volatile("s_waitcnt vmcnt(0) lgkmcnt(0)" ::: "memory");
    __builtin_amdgcn_s_barrier();
    SB0();

    uint4 pwN;
    for (int kg = 0; kg < NG; ++kg) {
        const bool last = (kg == NG - 1);
        DequantTab tab[2][2];
#pragma unroll
        for (int m = 0; m < 2; ++m)
#pragma unroll
            for (int n = 0; n < 2; ++n)
                tab[m][n] = build_tab(sc[m][n]);

        // ==== even step t0=2kg: consume buf0, stage buf1 ====
        *(uint4*)&wraw[1][mat][wrow][quad * 4] = pwA;     // w(t0+1)
        SB0();
#pragma unroll
        for (int j = 0; j < 4; ++j) gld16(xdst1[j], xsrc[j] + (kg * 2 + 1) * 64);
        SB0();
        { int tl = kg * 2 + 3; if (tl > NT - 1) tl = NT - 1;
          pwN = *(const uint4*)(wp_row + (size_t)tl * 8); }
        { const int kgn = last ? kg : kg + 1;
          scn[0][0] = gsc[(size_t)kgn * I_ + rb0]; scn[0][1] = gsc[(size_t)kgn * I_ + rb0 + 16];
          scn[1][0] = usc[(size_t)kgn * I_ + rb0]; scn[1][1] = usc[(size_t)kgn * I_ + rb0 + 16]; }
        SB0();
        MFMA1(xs0, 0);
        SB0();
        asm volatile("s_waitcnt vmcnt(5) lgkmcnt(0)" ::: "memory");
        __builtin_amdgcn_s_barrier();
        SB0();
        pwA = pwB; pwB = pwN;

        // ==== odd step t1=2kg+1: consume buf1, stage buf0 (if !last) ====
        if (!last) {
            *(uint4*)&wraw[0][mat][wrow][quad * 4] = pwA; // w(t1+1)
            SB0();
#pragma unroll
            for (int j = 0; j < 4; ++j) gld16(xdst0[j], xsrc[j] + (kg * 2 + 2) * 64);
            SB0();
            { int tl = kg * 2 + 4; if (tl > NT - 1) tl = NT - 1;
              pwN = *(const uint4*)(wp_row + (size_t)tl * 8); }
            SB0();
        }
        MFMA1(xs1, 1);
        SB0();
        if (!last) asm volatile("s_waitcnt vmcnt(1) lgkmcnt(0)" ::: "memory");
        else       asm volatile("s_waitcnt vmcnt(0) lgkmcnt(0)" ::: "memory");
        __builtin_amdgcn_s_barrier();
        SB0();
        if (!last) { pwA = pwB; pwB = pwN; }
#pragma unroll
        for (int m = 0; m < 2; ++m)
#pragma unroll
            for (int n = 0; n < 2; ++n) sc[m][n] = scn[m][n];
    }

    // epilogue: h = silu(g)*u. C layout: col=lane&15, row=(lane>>4)*4+r
#pragma unroll
    for (int mi = 0; mi < 4; ++mi)
#pragma unroll
        for (int n = 0; n < 2; ++n) {
            const int icol = itile * 64 + wx * 32 + n * 16 + lrow;
#pragma unroll
            for (int r = 0; r < 4; ++r) {
                const int grow = ty * 128 + wy * 64 + mi * 16 + kq * 4 + r;
                if (grow < cnt) {
                    const float gv = accg[mi][n][r];
                    const float hv = gv / (1.f + __expf(-gv)) * accu[mi][n][r];
                    h_buf[(size_t)(row0 + grow) * I_ + icol] = (bf16)hv;
                }
            }
        }
#undef MFMA1
}

// ---------------- GEMM2: 128tok x 128h, BK=64, RAW-u32 weight LDS ----------------
__global__ __launch_bounds__(256, 2)
void gemm2t_kernel(const bf16* __restrict__ h_buf,
                   const uint32_t* __restrict__ down_packed,
                   const float* __restrict__ down_scales,
                   const int* __restrict__ offsets,
                   const int* __restrict__ tmap,
                   const float* __restrict__ wgt, float* __restrict__ yp)
{
    const int tm = tmap[blockIdx.x];
    if (tm < 0) return;
    const int e = tm >> 16, ty = tm & 0xffff;
    const int row0 = offsets[e];
    const int cnt = offsets[e + 1] - row0;
    const int htile = blockIdx.y;                    // 128 h-cols

    __shared__ __align__(16) bf16 hs0[128][64];      // 16 KB
    __shared__ __align__(16) bf16 hs1[128][64];      // 16 KB
    __shared__ __align__(16) uint32_t wraw[2][128][12]; // 12 KB

    const int tid = threadIdx.x;

    const int xr = tid >> 3;
    const int xc = tid & 7;
    const int xch = (xc ^ (xr & 7)) * 8;
    const bf16* hsrc[4];
    bf16 *hdst0[4], *hdst1[4];
#pragma unroll
    for (int j = 0; j < 4; ++j) {
        int g = ty * 128 + xr + j * 32;
        g = (g < cnt) ? g : (cnt - 1);
        hsrc[j] = h_buf + (size_t)(row0 + g) * I_ + xch;
        hdst0[j] = &hs0[xr + j * 32][xc * 8];
        hdst1[j] = &hs1[xr + j * 32][xc * 8];
    }

    // weight staging: 128 rows x 8 u32 -> 1 raw uint4 per thread/step
    const int wrow = tid >> 1;           // 0..127
    const int quad = tid & 1;
    const int hrow = htile * 128 + wrow;
    const uint32_t* dp_row = down_packed + (size_t)e * H_ * (I_ / 8) + (size_t)hrow * (I_ / 8) + quad * 4;

    const int wave = tid >> 6, lane = tid & 63;
    const int wy = wave >> 1, wx = wave & 1;
    const int lrow = lane & 15, kq = lane >> 4;

    const float* dsc = down_scales + (size_t)e * (I_ / G_) * H_;
    const int rb0 = htile * 128 + wx * 64 + lrow;    // ni at +16*ni
    const int rbr0 = wx * 64 + lrow;                 // LDS weight row

    f32x4 acc[4][4] = {};

    constexpr int NG = I_ / G_;          // 11 kg; 22 K-steps
    constexpr int NT = 2 * NG;

#define MFMA2(HS, WB) do { \
    _Pragma("unroll") \
    for (int kh = 0; kh < 2; ++kh) { \
        bf16x8 a[4], b[4]; \
        _Pragma("unroll") \
        for (int mi = 0; mi < 4; ++mi) { \
            const int ra = wy * 64 + mi * 16 + lrow; \
            a[mi] = *(const bf16x8*)&HS[ra][((kh * 4 + kq) ^ (ra & 7)) * 8]; \
        } \
        _Pragma("unroll") \
        for (int n = 0; n < 4; ++n) \
            b[n] = dq_frag(wraw[WB][rbr0 + n * 16][kh * 4 + kq], tab[n]); \
        _Pragma("unroll") \
        for (int mi = 0; mi < 4; ++mi) \
            _Pragma("unroll") \
            for (int n = 0; n < 4; ++n) \
                acc[mi][n] = __builtin_amdgcn_mfma_f32_16x16x32_bf16(a[mi], b[n], acc[mi][n], 0, 0, 0); \
    } \
} while (0)

    // prologue
#pragma unroll
    for (int j = 0; j < 4; ++j) gld16(hdst0[j], hsrc[j]);
    SB0();
    uint4 pw0 = *(const uint4*)(dp_row);
    uint4 pwA = *(const uint4*)(dp_row + 8);
    uint4 pwB = *(const uint4*)(dp_row + 16);
    float sc[4], scn[4];
    sc[0] = dsc[rb0]; sc[1] = dsc[rb0 + 16]; sc[2] = dsc[rb0 + 32]; sc[3] = dsc[rb0 + 48];
    SB0();
    *(uint4*)&wraw[0][wrow][quad * 4] = pw0;
    asm volatile("s_waitcnt vmcnt(0) lgkmcnt(0)" ::: "memory");
    __builtin_amdgcn_s_barrier();
    SB0();

    uint4 pwN;
    for (int kg = 0; kg < NG; ++kg) {
        const bool last = (kg == NG - 1);
        DequantTab tab[4];
#pragma unroll
        for (int n = 0; n < 4; ++n) tab[n] = build_tab(sc[n]);

        // ==== even step ====
        *(uint4*)&wraw[1][wrow][quad * 4] = pwA;
        SB0();
#pragma unroll
        for (int j = 0; j < 4; ++j) gld16(hdst1[j], hsrc[j] + (kg * 2 + 1) * 64);
        SB0();
        { int tl = kg * 2 + 3; if (tl > NT - 1) tl = NT - 1;
          pwN = *(const uint4*)(dp_row + (size_t)tl * 8); }
        { const int kgn = last ? kg : kg + 1;
          scn[0] = dsc[(size_t)kgn * H_ + rb0];      scn[1] = dsc[(size_t)kgn * H_ + rb0 + 16];
          scn[2] = dsc[(size_t)kgn * H_ + rb0 + 32]; scn[3] = dsc[(size_t)kgn * H_ + rb0 + 48]; }
        SB0();
        MFMA2(hs0, 0);
        SB0();
        asm volatile("s_waitcnt vmcnt(5) lgkmcnt(0)" ::: "memory");
        __builtin_amdgcn_s_barrier();
        SB0();
        pwA = pwB; pwB = pwN;

        // ==== odd step ====
        if (!last) {
            *(uint4*)&wraw[0][wrow][quad * 4] = pwA;
            SB0();
#pragma unroll
            for (int j = 0; j < 4; ++j) gld16(hdst0[j], hsrc[j] + (kg * 2 + 2) * 64);
            SB0();
            { int tl = kg * 2 + 4; if (tl > NT - 1) tl = NT - 1;
              pwN = *(const uint4*)(dp_row + (size_t)tl * 8); }
            SB0();
        }
        MFMA2(hs1, 1);
        SB0();
        if (!last) asm volatile("s_waitcnt vmcnt(1) lgkmcnt(0)" ::: "memory");
        else       asm volatile("s_waitcnt vmcnt(0) lgkmcnt(0)" ::: "memory");
        __builtin_amdgcn_s_barrier();
        SB0();
        if (!last) { pwA = pwB; pwB = pwN; }
#pragma unroll
        for (int n = 0; n < 4; ++n) sc[n] = scn[n];
    }

    // epilogue: plain stores of wgt-scaled partials
#pragma unroll
    for (int mi = 0; mi < 4; ++mi)
#pragma unroll
        for (int r = 0; r < 4; ++r) {
            const int grow = ty * 128 + wy * 64 + mi * 16 + kq * 4 + r;
            if (grow < cnt) {
                const float w = wgt[row0 + grow];
#pragma unroll
                for (int n = 0; n < 4; ++n) {
                    const int col = htile * 128 + wx * 64 + n * 16 + lrow;
                    yp[(size_t)(row0 + grow) * H_ + col] = acc[mi][n][r] * w;
                }
            }
        }
#undef MFMA2
}

// ---------------- combine: out[t] = sum over K pairs ----------------
__global__ __launch_bounds__(256)
void combine_kernel(const float* __restrict__ yp, const int* __restrict__ inv,
                    float* __restrict__ out) {
    const int idx = blockIdx.x * 256 + threadIdx.x;   // T_*H_/4 units
    const int t = idx >> 9;                            // / (H_/4 = 512)
    const int c = idx & 511;
    const float4 a = ((const float4*)yp)[(size_t)inv[t * 2] * (H_ / 4) + c];
    const float4 b = ((const float4*)yp)[(size_t)inv[t * 2 + 1] * (H_ / 4) + c];
    float4 o;
    o.x = a.x + b.x; o.y = a.y + b.y; o.z = a.z + b.z; o.w = a.w + b.w;
    ((float4*)out)[idx] = o;
}

extern "C" void kernel_launch(void* const* d_in, const int* in_sizes, int n_in,
                              void* d_out, int out_size, void* d_ws, size_t ws_size,
                              hipStream_t stream) {
    const float* x = (const float*)d_in[0];
    const uint32_t* gate_packed = (const uint32_t*)d_in[1];
    const float* gate_scales = (const float*)d_in[2];
    const uint32_t* up_packed = (const uint32_t*)d_in[3];
    const float* up_scales = (const float*)d_in[4];
    const uint32_t* down_packed = (const uint32_t*)d_in[5];
    const float* down_scales = (const float*)d_in[6];
    const int* topk_idx = (const int*)d_in[7];
    const float* topk_w = (const float*)d_in[8];
    float* out = (float*)d_out;

    // workspace layout (bytes)
    char* ws = (char*)d_ws;
    int* counts  = (int*)ws;              // 32
    int* cursors = (int*)(ws + 32);       // 32
    int* offsets = (int*)(ws + 64);       // 64
    int* tmap    = (int*)(ws + 128);      // 256 (64 ints)
    int* tok     = (int*)(ws + 640);      // 16384
    float* wgt   = (float*)(ws + 17024);  // 16384
    int* inv     = (int*)(ws + 33408);    // 16384
    bf16* h_buf  = (bf16*)(ws + 49792);   // 11,534,336
    bf16* xb     = (bf16*)(ws + 49792 + 11534336ull);                 // 8,388,608
    float* yp    = (float*)(ws + 49792 + 11534336ull + 8388608ull);   // 33,554,432

    hipMemsetAsync(d_ws, 0, 1024, stream);

    route_count<<<(T_ * K_ + 255) / 256, 256, 0, stream>>>(topk_idx, counts);
    route_scan<<<1, 64, 0, stream>>>(counts, offsets, tmap);
    route_fill<<<(T_ * K_ + 255) / 256, 256, 0, stream>>>(topk_idx, topk_w, cursors, offsets,
                                                          tok, wgt, inv);
    xcast_kernel<<<T_ * H_ / 8 / 256, 256, 0, stream>>>(x, (uint4*)xb);

    dim3 g1(40, I_ / 64);    // x = 128-token tile (weight reuse), y = itile
    gemm1t_kernel<<<g1, 256, 0, stream>>>(xb, gate_packed, gate_scales, up_packed, up_scales,
                                          offsets, tmap, tok, h_buf);
    dim3 g2(40, H_ / 128);   // x = 128-token tile, y = htile
    gemm2t_kernel<<<g2, 256, 0, stream>>>(h_buf, down_packed, down_scales,
                                          offsets, tmap, wgt, yp);
    combine_kernel<<<T_ * H_ / 4 / 256, 256, 0, stream>>>(yp, inv, out);
}

// Round 8
// 273.293 us; speedup vs baseline: 1.3369x; 1.0838x over previous
//
#include <hip/hip_runtime.h>
#include <hip/hip_bf16.h>
#include <stdint.h>

#define E_ 8
#define H_ 2048
#define I_ 1408
#define T_ 2048
#define K_ 2
#define G_ 128

typedef __bf16 bf16;
typedef bf16 bf16x8 __attribute__((ext_vector_type(8)));
typedef float f32x4 __attribute__((ext_vector_type(4)));

__device__ __forceinline__ uint32_t prm(uint32_t hi, uint32_t lo, uint32_t sel) {
    return __builtin_amdgcn_perm(hi, lo, sel);
}

// Scale-folded dequant tables: bf16(e2m1[m]*s) split into high/low byte LUTs.
struct DequantTab { uint32_t thi0, thi1, tlo0, tlo1; };

__device__ __forceinline__ DequantTab build_tab(float s) {
    union { bf16 h[8]; uint32_t u[4]; } tb;
    tb.h[0] = (bf16)(0.0f);
    tb.h[1] = (bf16)(0.5f * s);
    tb.h[2] = (bf16)(1.0f * s);
    tb.h[3] = (bf16)(1.5f * s);
    tb.h[4] = (bf16)(2.0f * s);
    tb.h[5] = (bf16)(3.0f * s);
    tb.h[6] = (bf16)(4.0f * s);
    tb.h[7] = (bf16)(6.0f * s);
    DequantTab t;
    t.thi0 = prm(tb.u[1], tb.u[0], 0x07050301u);
    t.tlo0 = prm(tb.u[1], tb.u[0], 0x06040200u);
    t.thi1 = prm(tb.u[3], tb.u[2], 0x07050301u);
    t.tlo1 = prm(tb.u[3], tb.u[2], 0x06040200u);
    return t;
}

// 8 fp4 (one u32, k-order) -> 8 scaled bf16 as uint4. ~21 VALU ops.
__device__ __forceinline__ uint4 dequant8t(uint32_t p, const DequantTab& t) {
    const uint32_t pr = p >> 4;
    const uint32_t pe = p  & 0x07070707u;
    const uint32_t po = pr & 0x07070707u;
    const uint32_t He = prm(t.thi1, t.thi0, pe) | ((p  & 0x08080808u) << 4);
    const uint32_t Le = prm(t.tlo1, t.tlo0, pe);
    const uint32_t Ho = prm(t.thi1, t.thi0, po) | ((pr & 0x08080808u) << 4);
    const uint32_t Lo = prm(t.tlo1, t.tlo0, po);
    const uint32_t E01 = prm(He, Le, 0x05010400u);
    const uint32_t E23 = prm(He, Le, 0x07030602u);
    const uint32_t O01 = prm(Ho, Lo, 0x05010400u);
    const uint32_t O23 = prm(Ho, Lo, 0x07030602u);
    return make_uint4(prm(O01, E01, 0x05040100u),
                      prm(O01, E01, 0x07060302u),
                      prm(O23, E23, 0x05040100u),
                      prm(O23, E23, 0x07060302u));
}

// async 16B global -> LDS DMA (wave-uniform-base + lane-linear dest)
__device__ __forceinline__ void gld16(void* lds, const void* g) {
    __builtin_amdgcn_global_load_lds(
        (__attribute__((address_space(1))) void*)g,
        (__attribute__((address_space(3))) void*)lds, 16, 0, 0);
}

#define SB0() __builtin_amdgcn_sched_barrier(0)

// dequant one uint4 (4 u32 = one 64-k row-slice) into swizzled LDS tile WD
#define DQW(WD, PW, TAB) do { \
    uint4 d0_ = dequant8t((PW).x, (TAB)); \
    uint4 d1_ = dequant8t((PW).y, (TAB)); \
    uint4 d2_ = dequant8t((PW).z, (TAB)); \
    uint4 d3_ = dequant8t((PW).w, (TAB)); \
    *(uint4*)&WD[wrow][((cb + 0) ^ rs) * 8] = d0_; \
    *(uint4*)&WD[wrow][((cb + 1) ^ rs) * 8] = d1_; \
    *(uint4*)&WD[wrow][((cb + 2) ^ rs) * 8] = d2_; \
    *(uint4*)&WD[wrow][((cb + 3) ^ rs) * 8] = d3_; \
} while (0)

// ---------------- routing ----------------
__global__ void route_count(const int* __restrict__ topk_idx, int* __restrict__ counts) {
    int p = blockIdx.x * blockDim.x + threadIdx.x;
    if (p < T_ * K_) atomicAdd(&counts[topk_idx[p]], 1);
}

// dense list of 128-row tiles; ntiles stored in offsets[9]
__global__ void route_scan(const int* __restrict__ counts, int* __restrict__ offsets,
                           int* __restrict__ tmap) {
    if (threadIdx.x == 0) {
        int acc = 0, ti = 0;
        for (int e = 0; e < E_; e++) {
            offsets[e] = acc;
            int nt = (counts[e] + 127) >> 7;
            for (int j = 0; j < nt; j++) tmap[ti++] = (e << 16) | j;
            acc += counts[e];
        }
        offsets[E_] = acc;
        offsets[E_ + 1] = ti;            // ntiles
        for (; ti < 64; ti++) tmap[ti] = -1;
    }
}

__global__ void route_fill(const int* __restrict__ topk_idx, const float* __restrict__ topk_w,
                           int* __restrict__ cursors, const int* __restrict__ offsets,
                           int* __restrict__ tok, float* __restrict__ wgt,
                           int* __restrict__ inv) {
    int p = blockIdx.x * blockDim.x + threadIdx.x;
    if (p < T_ * K_) {
        int e = topk_idx[p];
        int slot = atomicAdd(&cursors[e], 1);
        int idx = offsets[e] + slot;
        tok[idx] = p / K_;
        wgt[idx] = topk_w[p];
        inv[p] = idx;
    }
}

// x f32 -> bf16
__global__ __launch_bounds__(256)
void xcast_kernel(const float* __restrict__ x, uint4* __restrict__ xb) {
    const int i = blockIdx.x * 256 + threadIdx.x;
    const float4 a = ((const float4*)x)[i * 2];
    const float4 b = ((const float4*)x)[i * 2 + 1];
    union { uint4 u; bf16 h[8]; } r;
    r.h[0] = (bf16)a.x; r.h[1] = (bf16)a.y; r.h[2] = (bf16)a.z; r.h[3] = (bf16)a.w;
    r.h[4] = (bf16)b.x; r.h[5] = (bf16)b.y; r.h[6] = (bf16)b.z; r.h[7] = (bf16)b.w;
    xb[i] = r.u;
}

// ---------------- GEMM1: persistent 512-block grid, 128tok x 64i, BK=64 ----------------
// R5 inner loop verbatim (w-LDS double-buffered, 1 barrier/K-step). Outer:
// persistent work loop over dense (ttile, itile) list -> zero generation tail.
__global__ __launch_bounds__(256, 2)
void gemm1t_kernel(const bf16* __restrict__ xb,
                   const uint32_t* __restrict__ gate_packed,
                   const float* __restrict__ gate_scales,
                   const uint32_t* __restrict__ up_packed,
                   const float* __restrict__ up_scales,
                   const int* __restrict__ offsets,
                   const int* __restrict__ tmap,
                   const int* __restrict__ tok, bf16* __restrict__ h_buf)
{
    __shared__ __align__(16) bf16 xs0[128][64];      // 16 KB
    __shared__ __align__(16) bf16 xs1[128][64];      // 16 KB
    __shared__ __align__(16) bf16 wgs0[64][64];      // 8 KB
    __shared__ __align__(16) bf16 wgs1[64][64];
    __shared__ __align__(16) bf16 wus0[64][64];
    __shared__ __align__(16) bf16 wus1[64][64];      // total 64 KB

    const int tid = threadIdx.x;
    const int ntiles = offsets[E_ + 1];
    const int nwork = ntiles * 22;

    const int xr = tid >> 3;             // 0..31
    const int xc = tid & 7;
    const int xch = (xc ^ (xr & 7)) * 8;

    const int mat  = tid >> 7;           // 0 = gate, 1 = up
    const int id   = tid & 127;
    const int wrow = id >> 1;            // 0..63
    const int quad = id & 1;
    const int cb = quad * 4, rs = wrow & 7;

    const int wave = tid >> 6, lane = tid & 63;
    const int wy = wave >> 1, wx = wave & 1;
    const int lrow = lane & 15, kq = lane >> 4;

    constexpr int NG = H_ / G_;          // 16 kg; 32 K-steps

#define MFMA1(XS, WG, WU) do { \
    _Pragma("unroll") \
    for (int kh = 0; kh < 2; ++kh) { \
        bf16x8 a[4], bg[2], bu[2]; \
        _Pragma("unroll") \
        for (int mi = 0; mi < 4; ++mi) { \
            const int ra = wy * 64 + mi * 16 + lrow; \
            a[mi] = *(const bf16x8*)&XS[ra][((kh * 4 + kq) ^ (ra & 7)) * 8]; \
        } \
        _Pragma("unroll") \
        for (int ni = 0; ni < 2; ++ni) { \
            const int rbq = wx * 32 + ni * 16 + lrow; \
            const int cbq = ((kh * 4 + kq) ^ (rbq & 7)) * 8; \
            bg[ni] = *(const bf16x8*)&WG[rbq][cbq]; \
            bu[ni] = *(const bf16x8*)&WU[rbq][cbq]; \
        } \
        _Pragma("unroll") \
        for (int mi = 0; mi < 4; ++mi) \
            _Pragma("unroll") \
            for (int ni = 0; ni < 2; ++ni) { \
                accg[mi][ni] = __builtin_amdgcn_mfma_f32_16x16x32_bf16(a[mi], bg[ni], accg[mi][ni], 0, 0, 0); \
                accu[mi][ni] = __builtin_amdgcn_mfma_f32_16x16x32_bf16(a[mi], bu[ni], accu[mi][ni], 0, 0, 0); \
            } \
    } \
} while (0)

    for (int wk = blockIdx.x; wk < nwork; wk += gridDim.x) {
        const int wt = wk / 22;
        const int itile = wk - wt * 22;              // 0..21 (64 i-cols)
        const int tm = tmap[wt];
        const int e = tm >> 16, ty = tm & 0xffff;    // 128-token tile
        const int row0 = offsets[e];
        const int cnt = offsets[e + 1] - row0;

        // --- x staging roles: 4 gld16/thread/step, swizzled source chunk ---
        const bf16* xsrc[4];
        bf16 *xdst0[4], *xdst1[4];
#pragma unroll
        for (int j = 0; j < 4; ++j) {
            int g = ty * 128 + xr + j * 32;
            g = (g < cnt) ? g : (cnt - 1);
            xsrc[j] = xb + (size_t)tok[row0 + g] * H_ + xch;
            xdst0[j] = &xs0[xr + j * 32][xc * 8];
            xdst1[j] = &xs1[xr + j * 32][xc * 8];
        }

        // --- weight roles ---
        const int irow = itile * 64 + wrow;
        const uint32_t* wp_row = (mat ? up_packed : gate_packed)
            + (size_t)e * I_ * (H_ / 8) + (size_t)irow * (H_ / 8) + quad * 4;
        const float* ws_row = (mat ? up_scales : gate_scales)
            + (size_t)e * (H_ / G_) * I_ + irow;
        bf16 (* const wd0)[64] = mat ? wus0 : wgs0;
        bf16 (* const wd1)[64] = mat ? wus1 : wgs1;

        f32x4 accg[4][2] = {};
        f32x4 accu[4][2] = {};

        // ---------------- prologue: D(0), P(0), P(1), S(0); dequant(0)->w0 ----------------
#pragma unroll
        for (int j = 0; j < 4; ++j) gld16(xdst0[j], xsrc[j]);
        SB0();
        uint4 pw0 = *(const uint4*)(wp_row);
        uint4 pwO = *(const uint4*)(wp_row + 8);
        float sc0 = ws_row[0];
        SB0();
        DequantTab tab = build_tab(sc0);     // auto-wait drains D(0)+P loads too
        DQW(wd0, pw0, tab);
        asm volatile("s_waitcnt lgkmcnt(0)" ::: "memory");
        __builtin_amdgcn_s_barrier();
        SB0();

        float scn = 0.f;
        uint4 pwE;
        for (int kg = 0; kg < NG; ++kg) {
            const bool last = (kg == NG - 1);
            // ==== even step t0=2kg: compute buf0; fill buf1 ====
#pragma unroll
            for (int j = 0; j < 4; ++j) gld16(xdst1[j], xsrc[j] + (kg * 2 + 1) * 64);
            SB0();
            if (!last) {
                pwE = *(const uint4*)(wp_row + (size_t)(kg * 2 + 2) * 8);
                scn = ws_row[(size_t)(kg + 1) * I_];
            }
            SB0();
            DQW(wd1, pwO, tab);              // dequant(t0+1), same kg
            MFMA1(xs0, wgs0, wus0);          // compute(t0) -- interleaves with DQW
            SB0();
            if (!last) asm volatile("s_waitcnt vmcnt(2) lgkmcnt(0)" ::: "memory");
            else       asm volatile("s_waitcnt vmcnt(0) lgkmcnt(0)" ::: "memory");
            __builtin_amdgcn_s_barrier();
            SB0();

            // ==== odd step t1=2kg+1: compute buf1; fill buf0 (if !last) ====
            if (!last) {
#pragma unroll
                for (int j = 0; j < 4; ++j) gld16(xdst0[j], xsrc[j] + (kg * 2 + 2) * 64);
                SB0();
                pwO = *(const uint4*)(wp_row + (size_t)(kg * 2 + 3) * 8);
                SB0();
                tab = build_tab(scn);        // kg+1 table
                DQW(wd0, pwE, tab);          // dequant(t1+1) = even step of kg+1
                MFMA1(xs1, wgs1, wus1);      // compute(t1)
                SB0();
                asm volatile("s_waitcnt vmcnt(1) lgkmcnt(0)" ::: "memory");
                __builtin_amdgcn_s_barrier();
                SB0();
            } else {
                MFMA1(xs1, wgs1, wus1);      // compute(NT-1)
                SB0();
                asm volatile("s_waitcnt lgkmcnt(0)" ::: "memory");
                __builtin_amdgcn_s_barrier();
                SB0();
            }
        }

        // epilogue: h = silu(g)*u. C layout: col=lane&15, row=(lane>>4)*4+r
#pragma unroll
        for (int mi = 0; mi < 4; ++mi)
#pragma unroll
            for (int ni = 0; ni < 2; ++ni) {
                const int icol = itile * 64 + wx * 32 + ni * 16 + lrow;
#pragma unroll
                for (int r = 0; r < 4; ++r) {
                    const int grow = ty * 128 + wy * 64 + mi * 16 + kq * 4 + r;
                    if (grow < cnt) {
                        const float gv = accg[mi][ni][r];
                        const float hv = gv / (1.f + __expf(-gv)) * accu[mi][ni][r];
                        h_buf[(size_t)(row0 + grow) * I_ + icol] = (bf16)hv;
                    }
                }
            }
        // ensure epilogue stores ordered before next iteration's barrier use of LDS
        __builtin_amdgcn_s_barrier();
    }
#undef MFMA1
}

// ---------------- GEMM2: persistent 512-block grid, 128tok x 128h, BK=64 ----------------
__global__ __launch_bounds__(256, 2)
void gemm2t_kernel(const bf16* __restrict__ h_buf,
                   const uint32_t* __restrict__ down_packed,
                   const float* __restrict__ down_scales,
                   const int* __restrict__ offsets,
                   const int* __restrict__ tmap,
                   const float* __restrict__ wgt, float* __restrict__ yp)
{
    __shared__ __align__(16) bf16 hs0[128][64];      // 16 KB
    __shared__ __align__(16) bf16 hs1[128][64];
    __shared__ __align__(16) bf16 wds0[128][64];     // 16 KB
    __shared__ __align__(16) bf16 wds1[128][64];     // total 64 KB

    const int tid = threadIdx.x;
    const int ntiles = offsets[E_ + 1];
    const int nwork = ntiles * 16;

    const int xr = tid >> 3;
    const int xc = tid & 7;
    const int xch = (xc ^ (xr & 7)) * 8;

    const int wrow = tid >> 1;           // 0..127
    const int quad = tid & 1;
    const int cb = quad * 4, rs = wrow & 7;

    const int wave = tid >> 6, lane = tid & 63;
    const int wy = wave >> 1, wx = wave & 1;
    const int lrow = lane & 15, kq = lane >> 4;

    constexpr int NG = I_ / G_;          // 11 kg; 22 K-steps

#define MFMA2(HS, WD) do { \
    _Pragma("unroll") \
    for (int kh = 0; kh < 2; ++kh) { \
        bf16x8 a[4], b[4]; \
        _Pragma("unroll") \
        for (int mi = 0; mi < 4; ++mi) { \
            const int ra = wy * 64 + mi * 16 + lrow; \
            a[mi] = *(const bf16x8*)&HS[ra][((kh * 4 + kq) ^ (ra & 7)) * 8]; \
        } \
        _Pragma("unroll") \
        for (int ni = 0; ni < 4; ++ni) { \
            const int rbq = wx * 64 + ni * 16 + lrow; \
            b[ni] = *(const bf16x8*)&WD[rbq][((kh * 4 + kq) ^ (rbq & 7)) * 8]; \
        } \
        _Pragma("unroll") \
        for (int mi = 0; mi < 4; ++mi) \
            _Pragma("unroll") \
            for (int ni = 0; ni < 4; ++ni) \
                acc[mi][ni] = __builtin_amdgcn_mfma_f32_16x16x32_bf16(a[mi], b[ni], acc[mi][ni], 0, 0, 0); \
    } \
} while (0)

    for (int wk = blockIdx.x; wk < nwork; wk += gridDim.x) {
        const int wt = wk >> 4;
        const int htile = wk & 15;                   // 128 h-cols
        const int tm = tmap[wt];
        const int e = tm >> 16, ty = tm & 0xffff;
        const int row0 = offsets[e];
        const int cnt = offsets[e + 1] - row0;

        const bf16* hsrc[4];
        bf16 *hdst0[4], *hdst1[4];
#pragma unroll
        for (int j = 0; j < 4; ++j) {
            int g = ty * 128 + xr + j * 32;
            g = (g < cnt) ? g : (cnt - 1);
            hsrc[j] = h_buf + (size_t)(row0 + g) * I_ + xch;
            hdst0[j] = &hs0[xr + j * 32][xc * 8];
            hdst1[j] = &hs1[xr + j * 32][xc * 8];
        }

        const int hrow = htile * 128 + wrow;
        const uint32_t* dp_row = down_packed + (size_t)e * H_ * (I_ / 8) + (size_t)hrow * (I_ / 8) + quad * 4;
        const float* ds_row = down_scales + (size_t)e * (I_ / G_) * H_ + hrow;

        f32x4 acc[4][4] = {};

        // prologue
#pragma unroll
        for (int j = 0; j < 4; ++j) gld16(hdst0[j], hsrc[j]);
        SB0();
        uint4 pw0 = *(const uint4*)(dp_row);
        uint4 pwO = *(const uint4*)(dp_row + 8);
        float sc0 = ds_row[0];
        SB0();
        DequantTab tab = build_tab(sc0);
        DQW(wds0, pw0, tab);
        asm volatile("s_waitcnt lgkmcnt(0)" ::: "memory");
        __builtin_amdgcn_s_barrier();
        SB0();

        float scn = 0.f;
        uint4 pwE;
        for (int kg = 0; kg < NG; ++kg) {
            const bool last = (kg == NG - 1);
            // ==== even step ====
#pragma unroll
            for (int j = 0; j < 4; ++j) gld16(hdst1[j], hsrc[j] + (kg * 2 + 1) * 64);
            SB0();
            if (!last) {
                pwE = *(const uint4*)(dp_row + (size_t)(kg * 2 + 2) * 8);
                scn = ds_row[(size_t)(kg + 1) * H_];
            }
            SB0();
            DQW(wds1, pwO, tab);
            MFMA2(hs0, wds0);
            SB0();
            if (!last) asm volatile("s_waitcnt vmcnt(2) lgkmcnt(0)" ::: "memory");
            else       asm volatile("s_waitcnt vmcnt(0) lgkmcnt(0)" ::: "memory");
            __builtin_amdgcn_s_barrier();
            SB0();

            // ==== odd step ====
            if (!last) {
#pragma unroll
                for (int j = 0; j < 4; ++j) gld16(hdst0[j], hsrc[j] + (kg * 2 + 2) * 64);
                SB0();
                pwO = *(const uint4*)(dp_row + (size_t)(kg * 2 + 3) * 8);
                SB0();
                tab = build_tab(scn);
                DQW(wds0, pwE, tab);
                MFMA2(hs1, wds1);
                SB0();
                asm volatile("s_waitcnt vmcnt(1) lgkmcnt(0)" ::: "memory");
                __builtin_amdgcn_s_barrier();
                SB0();
            } else {
                MFMA2(hs1, wds1);
                SB0();
                asm volatile("s_waitcnt lgkmcnt(0)" ::: "memory");
                __builtin_amdgcn_s_barrier();
                SB0();
            }
        }

        // epilogue: plain stores of wgt-scaled partials
#pragma unroll
        for (int mi = 0; mi < 4; ++mi)
#pragma unroll
            for (int r = 0; r < 4; ++r) {
                const int lr = wy * 64 + mi * 16 + kq * 4 + r;
                const int grow = ty * 128 + lr;
                if (grow < cnt) {
                    const float w = wgt[row0 + grow];
#pragma unroll
                    for (int ni = 0; ni < 4; ++ni) {
                        const int col = htile * 128 + wx * 64 + ni * 16 + lrow;
                        yp[(size_t)(row0 + grow) * H_ + col] = acc[mi][ni][r] * w;
                    }
                }
            }
        __builtin_amdgcn_s_barrier();
    }
#undef MFMA2
}

// ---------------- combine: out[t] = sum over K pairs ----------------
__global__ __launch_bounds__(256)
void combine_kernel(const float* __restrict__ yp, const int* __restrict__ inv,
                    float* __restrict__ out) {
    const int idx = blockIdx.x * 256 + threadIdx.x;   // T_*H_/4 units
    const int t = idx >> 9;                            // / (H_/4 = 512)
    const int c = idx & 511;
    const float4 a = ((const float4*)yp)[(size_t)inv[t * 2] * (H_ / 4) + c];
    const float4 b = ((const float4*)yp)[(size_t)inv[t * 2 + 1] * (H_ / 4) + c];
    float4 o;
    o.x = a.x + b.x; o.y = a.y + b.y; o.z = a.z + b.z; o.w = a.w + b.w;
    ((float4*)out)[idx] = o;
}

extern "C" void kernel_launch(void* const* d_in, const int* in_sizes, int n_in,
                              void* d_out, int out_size, void* d_ws, size_t ws_size,
                              hipStream_t stream) {
    const float* x = (const float*)d_in[0];
    const uint32_t* gate_packed = (const uint32_t*)d_in[1];
    const float* gate_scales = (const float*)d_in[2];
    const uint32_t* up_packed = (const uint32_t*)d_in[3];
    const float* up_scales = (const float*)d_in[4];
    const uint32_t* down_packed = (const uint32_t*)d_in[5];
    const float* down_scales = (const float*)d_in[6];
    const int* topk_idx = (const int*)d_in[7];
    const float* topk_w = (const float*)d_in[8];
    float* out = (float*)d_out;

    // workspace layout (bytes)
    char* ws = (char*)d_ws;
    int* counts  = (int*)ws;              // 32
    int* cursors = (int*)(ws + 32);       // 32
    int* offsets = (int*)(ws + 64);       // 64 (offsets[9] = ntiles)
    int* tmap    = (int*)(ws + 128);      // 256 (64 ints)
    int* tok     = (int*)(ws + 640);      // 16384
    float* wgt   = (float*)(ws + 17024);  // 16384
    int* inv     = (int*)(ws + 33408);    // 16384
    bf16* h_buf  = (bf16*)(ws + 49792);   // 11,534,336
    bf16* xb     = (bf16*)(ws + 49792 + 11534336ull);                 // 8,388,608
    float* yp    = (float*)(ws + 49792 + 11534336ull + 8388608ull);   // 33,554,432

    hipMemsetAsync(d_ws, 0, 1024, stream);

    route_count<<<(T_ * K_ + 255) / 256, 256, 0, stream>>>(topk_idx, counts);
    route_scan<<<1, 64, 0, stream>>>(counts, offsets, tmap);
    route_fill<<<(T_ * K_ + 255) / 256, 256, 0, stream>>>(topk_idx, topk_w, cursors, offsets,
                                                          tok, wgt, inv);
    xcast_kernel<<<T_ * H_ / 8 / 256, 256, 0, stream>>>(x, (uint4*)xb);

    // persistent grids: 512 blocks = 2 blocks/CU x 256 CU, zero generation tail
    gemm1t_kernel<<<512, 256, 0, stream>>>(xb, gate_packed, gate_scales, up_packed, up_scales,
                                           offsets, tmap, tok, h_buf);
    gemm2t_kernel<<<512, 256, 0, stream>>>(h_buf, down_packed, down_scales,
                                           offsets, tmap, wgt, yp);
    combine_kernel<<<T_ * H_ / 4 / 256, 256, 0, stream>>>(yp, inv, out);
}